// Round 1
// 933.431 us; speedup vs baseline: 1.0916x; 1.0916x over previous
//
#include <hip/hip_runtime.h>
#include <math.h>

#define QDIM 256
#define KDIM 512
#define NB2  2048        // blocks in score kernel
#define TPB  256         // threads per block
#define WPB  (TPB / 64)  // waves per block = 4
#define TAIL_T 37.0f     // drop rows with s < m - T; weight <= N*e^-T ~ 2e-11 (provable bound)

// ---------------------------------------------------------------------------
// Kernel 1: q = W @ query + b.  W is [KDIM, QDIM] row-major.
// Wave-per-row: lane l loads W4[row*64 + l] (float4) and query4[l].
// 32 waves total (8 blocks x 256), 16 rows per wave.
// ---------------------------------------------------------------------------
__global__ __launch_bounds__(256) void qproj_kernel(const float* __restrict__ query,
                                                    const float* __restrict__ W,
                                                    const float* __restrict__ b,
                                                    float* __restrict__ q_out) {
    const int lane = threadIdx.x & 63;
    const int gw = (blockIdx.x * blockDim.x + threadIdx.x) >> 6;  // global wave 0..31
    const float4* W4 = (const float4*)W;
    const float4* q4 = (const float4*)query;
    float4 qv = q4[lane];
    const int row0 = gw * 16;
    for (int r = 0; r < 16; ++r) {
        const int row = row0 + r;
        float4 wv = W4[row * (QDIM / 4) + lane];
        float s = wv.x * qv.x + wv.y * qv.y + wv.z * qv.z + wv.w * qv.w;
#pragma unroll
        for (int i = 32; i >= 1; i >>= 1) s += __shfl_xor(s, i, 64);
        if (lane == 0) q_out[row] = s + b[row];
    }
}

// ---------------------------------------------------------------------------
// Kernel 2: stream key (512 MB) ONLY. Per row: coalesced float4 loads
// (64 lanes x 2 float4 = full 512-float row), butterfly dot-reduce,
// write score, wave-uniform online max/denominator update (no value work).
// 2048 blocks x 4 waves = 8192 waves = 32 waves/CU (max occupancy), 32 rows/wave.
// ---------------------------------------------------------------------------
__global__ __launch_bounds__(TPB) void score_kernel(
    const float* __restrict__ key, const float* __restrict__ q,
    float* __restrict__ scores, float* __restrict__ pm, float* __restrict__ pl,
    int N) {
    const int lane = threadIdx.x & 63;
    const int w = threadIdx.x >> 6;
    const int gw = blockIdx.x * WPB + w;
    const int total_waves = NB2 * WPB;
    const int rpw = (N + total_waves - 1) / total_waves;  // 32

    const float4* key4 = (const float4*)key;
    const float4* q4 = (const float4*)q;
    const float4 qa = q4[lane];
    const float4 qb = q4[64 + lane];

    float m = -INFINITY;
    float lsum = 0.0f;

    const long row0 = (long)gw * rpw;
    int rend = rpw;
    if (row0 + rend > N) rend = (int)(N - row0 > 0 ? N - row0 : 0);

#pragma unroll 2
    for (int r = 0; r < rend; ++r) {
        const long row = row0 + r;
        const long base = row * (KDIM / 4);  // 128 float4 per row
        float4 ka = key4[base + lane];
        float4 kb = key4[base + 64 + lane];
        float s = ka.x * qa.x + ka.y * qa.y + ka.z * qa.z + ka.w * qa.w +
                  kb.x * qb.x + kb.y * qb.y + kb.z * qb.z + kb.w * qb.w;
#pragma unroll
        for (int i = 32; i >= 1; i >>= 1) s += __shfl_xor(s, i, 64);
        if (lane == 0) scores[row] = s;
        if (s <= m) {                 // common path (wave-uniform branch)
            lsum += __expf(s - m);
        } else {                      // new max, fires ~log N times
            lsum = lsum * __expf(m - s) + 1.0f;
            m = s;
        }
    }

    // ---- block combine: 4 wave partials -> 1 block partial ----
    __shared__ float s_m[WPB], s_l[WPB];
    if (lane == 0) { s_m[w] = m; s_l[w] = lsum; }
    __syncthreads();
    if (threadIdx.x == 0) {
        float mb = s_m[0];
#pragma unroll
        for (int i = 1; i < WPB; ++i) mb = fmaxf(mb, s_m[i]);
        float lb = 0.0f;
        if (mb != -INFINITY) {
#pragma unroll
            for (int i = 0; i < WPB; ++i) lb += s_l[i] * __expf(s_m[i] - mb);
        }
        pm[blockIdx.x] = mb;
        pl[blockIdx.x] = lb;
    }
}

// ---------------------------------------------------------------------------
// Kernel 3: combine NB2 block partials -> global max m, denominator L.
// Also zero out[512]. One block of 256 threads; NB2/256 = 8 entries/thread.
// ---------------------------------------------------------------------------
__global__ __launch_bounds__(256) void reduce_kernel(
    const float* __restrict__ pm, const float* __restrict__ pl,
    float* __restrict__ red, float* __restrict__ out) {
    const int t = threadIdx.x;
    const int lane = t & 63;
    const int wid = t >> 6;
    __shared__ float s_red[4];
    __shared__ float s_gm;

    float m = -INFINITY;
    for (int i = t; i < NB2; i += 256) m = fmaxf(m, pm[i]);
#pragma unroll
    for (int i = 32; i >= 1; i >>= 1) m = fmaxf(m, __shfl_xor(m, i, 64));
    if (lane == 0) s_red[wid] = m;
    __syncthreads();
    if (t == 0) s_gm = fmaxf(fmaxf(s_red[0], s_red[1]), fmaxf(s_red[2], s_red[3]));
    __syncthreads();
    const float gm = s_gm;

    float l = 0.0f;
    for (int i = t; i < NB2; i += 256) l += pl[i] * __expf(pm[i] - gm);
#pragma unroll
    for (int i = 32; i >= 1; i >>= 1) l += __shfl_xor(l, i, 64);
    __syncthreads();  // protect s_red reuse
    if (lane == 0) s_red[wid] = l;
    __syncthreads();
    if (t == 0) {
        red[0] = gm;
        red[1] = s_red[0] + s_red[1] + s_red[2] + s_red[3];
    }
    out[t] = 0.0f;
    out[t + 256] = 0.0f;
}

// ---------------------------------------------------------------------------
// Kernel 4: select rows with s > gm - TAIL_T and accumulate w * value[row].
// Each block scans 256 consecutive scores (coalesced, ~L2-resident); passing
// rows go to an LDS list (capacity = chunk size: overflow impossible).
// Only blocks holding candidates touch value (~O(100) rows total) and
// atomicAdd their 512-float partial into out. Error bound: dropped mass
// <= N * e^-TAIL_T <= 2.3e-11 of L, data-independent.
// ---------------------------------------------------------------------------
__global__ __launch_bounds__(256) void gather_kernel(
    const float* __restrict__ scores, const float* __restrict__ value,
    const float* __restrict__ red, float* __restrict__ out, int N) {
    __shared__ int s_cnt;
    __shared__ int s_list[256];
    __shared__ float s_sc[256];
    const int t = threadIdx.x;
    if (t == 0) s_cnt = 0;
    __syncthreads();

    const float gm = red[0];
    const float inv_l = 1.0f / red[1];
    const long row = (long)blockIdx.x * 256 + t;
    if (row < N) {
        const float s = scores[row];
        if (s > gm - TAIL_T) {
            const int p = atomicAdd(&s_cnt, 1);
            s_list[p] = (int)row;
            s_sc[p] = s;
        }
    }
    __syncthreads();
    const int cnt = s_cnt;
    if (cnt == 0) return;

    const float2* val2 = (const float2*)value;
    float2 acc = {0.0f, 0.0f};
    for (int c = 0; c < cnt; ++c) {
        const long base2 = (long)s_list[c] * (KDIM / 2);  // 256 float2 per row
        const float wv = __expf(s_sc[c] - gm) * inv_l;
        const float2 v = val2[base2 + t];
        acc.x += wv * v.x;
        acc.y += wv * v.y;
    }
    atomicAdd(&out[2 * t], acc.x);
    atomicAdd(&out[2 * t + 1], acc.y);
}

extern "C" void kernel_launch(void* const* d_in, const int* in_sizes, int n_in,
                              void* d_out, int out_size, void* d_ws, size_t ws_size,
                              hipStream_t stream) {
    const float* query = (const float*)d_in[0];
    const float* key   = (const float*)d_in[1];
    const float* value = (const float*)d_in[2];
    const float* W     = (const float*)d_in[3];
    const float* b     = (const float*)d_in[4];
    float* out = (float*)d_out;
    const int N = in_sizes[1] / KDIM;

    float* ws     = (float*)d_ws;
    float* q      = ws;             // 512
    float* scores = q + KDIM;       // N floats (1 MB)
    float* pm     = scores + N;     // NB2
    float* pl     = pm + NB2;       // NB2
    float* red    = pl + NB2;       // 2: {gm, L}

    qproj_kernel<<<8, 256, 0, stream>>>(query, W, b, q);
    score_kernel<<<NB2, TPB, 0, stream>>>(key, q, scores, pm, pl, N);
    reduce_kernel<<<1, 256, 0, stream>>>(pm, pl, red, out);
    const int gblocks = (N + 255) / 256;
    gather_kernel<<<gblocks, 256, 0, stream>>>(scores, value, red, out, N);
}